// Round 5
// baseline (908.533 us; speedup 1.0000x reference)
//
#include <hip/hip_runtime.h>
#include <cstdint>
#include <cstddef>

#define TT 2048
#define BB 32
#define DD 256
#define HH 256

using bf16x8 = __attribute__((ext_vector_type(8))) short;
using f32x4  = __attribute__((ext_vector_type(4))) float;

// ws layout:
// [0..63]    counters: [0]=nseg, [1]=queue head
// [REC_OFF]  int4 records (unsorted), cap 32768
// [REC2_OFF] int4 records (sorted desc by length)
// [BF_OFF]   fragmentized bf16 weights: 768 frags x 512 ushort (768 KB)
static const size_t REC_OFF  = 64;
static const size_t REC2_OFF = REC_OFF  + (size_t)32768 * 16;
static const size_t BF_OFF   = REC2_OFF + (size_t)32768 * 16;

__device__ __forceinline__ uint16_t f2bf(float v) {
    unsigned int u = __float_as_uint(v);
    u += 0x7FFF + ((u >> 16) & 1);          // RNE
    return (uint16_t)(u >> 16);
}
__device__ __forceinline__ float bf2f(uint16_t h) {
    return __uint_as_float(((unsigned int)h) << 16);
}
__device__ __forceinline__ float sigmoidf_(float v) {
    return 1.f / (1.f + __expf(-v));
}
__device__ __forceinline__ float tanhf_(float v) {
    v = fminf(fmaxf(v, -30.f), 30.f);
    float e = __expf(-2.f * v);
    return (1.f - e) / (1.f + e);
}

// ---------------- weights f32 -> bf16 MFMA fragments ----------------
// frag f = (w*2+ct)*48 + g*8 + kk ; lane holds B[col=w*32+ct*16+(lane&15)][k0..k0+8)
// k0 = kk*32 + (lane>>4)*8 ; g in 0..5 = {ih_r, ih_z, ih_n, hh_r, hh_z, hh_n}
__global__ void k_prep(const float* __restrict__ Wih, const float* __restrict__ Whh,
                       uint16_t* __restrict__ BF) {
    int i = blockIdx.x * 256 + threadIdx.x;      // 0..49151
    if (i >= 768 * 64) return;
    int lane = i & 63, f = i >> 6;
    int kk = f & 7, t = f >> 3;
    int g = t % 6, wct = t / 6;
    int w = wct >> 1, ct = wct & 1;
    int col = w * 32 + ct * 16 + (lane & 15);
    int k0 = kk * 32 + ((lane >> 4) << 3);
    const float* W = (g < 3) ? Wih : Whh;
    const float* src = W + (size_t)((g % 3) * 256 + col) * DD + k0;
    bf16x8 v;
    #pragma unroll
    for (int e = 0; e < 8; ++e) v[e] = (short)f2bf(src[e]);
    *(bf16x8*)&BF[(size_t)f * 512 + lane * 8] = v;
}

// ---------------- per-batch segment metadata ----------------
__global__ void k_meta(const int* __restrict__ seg, const int* __restrict__ lengths,
                       int4* __restrict__ recs, int* __restrict__ counters,
                       float* __restrict__ outIdx) {
    int b = blockIdx.x;
    int tid = threadIdx.x;                          // 256 threads
    int len = lengths[b];
    const int* s = seg + (size_t)b * TT;
    const int CH = TT / 256;                        // 8
    int t0 = tid * CH;

    int cnt = 0;
    for (int t = t0; t < t0 + CH; ++t)
        cnt += (s[t] == 0 && t < len) ? 1 : 0;

    __shared__ int part[256];
    __shared__ int base;
    part[tid] = cnt;
    __syncthreads();
    if (tid == 0) {
        int run = 0;
        for (int i = 0; i < 256; ++i) { int v = part[i]; part[i] = run; run += v; }
        base = atomicAdd(&counters[0], run);
        outIdx[b] = (float)run;                     // idx[b] output (as float)
    }
    __syncthreads();

    int run = part[tid];
    for (int t = t0; t < t0 + CH; ++t) {
        if (s[t] == 0 && t < len) {
            int ss = t - 1;
            while (ss >= 0 && s[ss] != 0) --ss;     // previous boundary (any, incl. dead)
            int slot = base + run;
            if (slot < 32768) recs[slot] = make_int4(b, ss + 1, t, run);
            ++run;
        }
    }
}

// ---------------- counting sort by segment length, descending ----------------
__global__ void k_sort(const int4* __restrict__ recs, int4* __restrict__ recs2,
                       const int* __restrict__ counters) {
    __shared__ int hist[64];
    __shared__ int off[64];
    int n = counters[0]; if (n > 32768) n = 32768;
    int tid = threadIdx.x;   // 1024
    if (tid < 64) hist[tid] = 0;
    __syncthreads();
    for (int i = tid; i < n; i += 1024) {
        int4 r = recs[i];
        int len = r.z - r.y + 1;
        atomicAdd(&hist[min(len, 63)], 1);
    }
    __syncthreads();
    if (tid == 0) {
        int run = 0;
        for (int b = 63; b >= 0; --b) { off[b] = run; run += hist[b]; }
    }
    __syncthreads();
    if (tid < 64) hist[tid] = 0;     // reuse as cursors
    __syncthreads();
    for (int i = tid; i < n; i += 1024) {
        int4 r = recs[i];
        int len = r.z - r.y + 1;
        int b = min(len, 63);
        int pos = off[b] + atomicAdd(&hist[b], 1);
        recs2[pos] = r;
    }
}

// ---------------- persistent MFMA segment-packed GRU, M=32 ----------------
// 512 thr = 8 waves; wave w owns H-cols [w*32,(w+1)*32); 2 row-tiles of 16.
// acc[2][4][2] = 64 VGPRs; phase-split inner loop keeps total < 128 VGPRs
// so 2 WGs/CU (4 waves/SIMD) stay resident with zero scratch spill.
__global__ __launch_bounds__(512, 4) void k_main(
    const float* __restrict__ x, const uint16_t* __restrict__ BF,
    const float* __restrict__ b_ih, const float* __restrict__ b_hh,
    const int4* __restrict__ recs, int* __restrict__ counters,
    float* __restrict__ out)
{
    extern __shared__ uint16_t smem[];               // 64 KiB dynamic
    uint16_t* xH = smem;                             // [32][256]
    uint16_t* xL = smem + 8192;
    uint16_t* hH = smem + 16384;
    uint16_t* hL = smem + 24576;
    __shared__ int rb[32], rt[32], re[32], rp[32], alive[32];
    __shared__ int liveRTS[2];
    __shared__ int anyAliveS, nsegS;

    const int tid  = threadIdx.x;
    const int lane = tid & 63;
    const int w    = tid >> 6;
    const int lcol = lane & 15;
    const int lk   = lane >> 4;

    for (int i = tid; i < 8192; i += 512) { hH[i] = 0; hL[i] = 0; }
    if (tid < 32) alive[tid] = 0;
    if (tid == 0) nsegS = min(counters[0], 32768);
    __syncthreads();
    const int nseg = nsegS;

    float bR[2], bZ[2], bIN[2], bHN[2];
    #pragma unroll
    for (int ct = 0; ct < 2; ++ct) {
        int c = w * 32 + ct * 16 + lcol;
        bR[ct]  = b_ih[c]       + b_hh[c];
        bZ[ct]  = b_ih[256 + c] + b_hh[256 + c];
        bIN[ct] = b_ih[512 + c];
        bHN[ct] = b_hh[512 + c];
    }
    const uint16_t* BFw = BF + (size_t)w * 96 * 512;

    for (;;) {
        // ---- pop/advance: wave 0, lane m owns slot m ----
        if (tid < 32) {
            int m = tid;
            int al = alive[m];
            if (al) { if (rt[m] >= re[m]) al = 0; else rt[m] = rt[m] + 1; }
            unsigned long long deadm = __ballot(!al);
            int base = 0;
            if (tid == 0 && deadm) base = atomicAdd(&counters[1], __popcll(deadm));
            base = __shfl(base, 0);
            if (!al) {
                int rank = __popcll(deadm & ((1ULL << tid) - 1));
                int sidx = base + rank;
                if (sidx < nseg) {
                    int4 r = recs[sidx];
                    rb[m] = r.x; rt[m] = r.y; re[m] = r.z; rp[m] = r.w;
                    al = 1;                          // h row is zero already
                }
            }
            alive[m] = al;
            unsigned long long am = __ballot(al);
            if (tid == 0) anyAliveS = (am != 0ULL) ? 1 : 0;
            if (tid < 2) liveRTS[tid] = (int)((am >> (tid * 16)) & 0xFFFFULL);
        }
        __syncthreads();
        if (!anyAliveS) break;

        // ---- stage x rows: 16 threads/row, hi/lo split, swizzled ----
        {
            int row = tid >> 4, j = tid & 15;
            if (alive[row]) {
                const float* xp = x + ((size_t)rb[row] * TT + rt[row]) * DD + j * 16;
                #pragma unroll
                for (int u = 0; u < 2; ++u) {
                    float4 a = *(const float4*)(xp + u * 8);
                    float4 b = *(const float4*)(xp + u * 8 + 4);
                    float vv[8] = {a.x, a.y, a.z, a.w, b.x, b.y, b.z, b.w};
                    bf16x8 vh, vl;
                    #pragma unroll
                    for (int e = 0; e < 8; ++e) {
                        uint16_t hi = f2bf(vv[e]);
                        vh[e] = (short)hi;
                        vl[e] = (short)f2bf(vv[e] - bf2f(hi));
                    }
                    int cs = j * 2 + u;
                    int o = row * 256 + ((cs ^ (row & 15)) << 3);
                    *(bf16x8*)&xH[o] = vh;
                    *(bf16x8*)&xL[o] = vl;
                }
            }
        }
        __syncthreads();

        const int lv0 = liveRTS[0], lv1 = liveRTS[1];

        f32x4 acc[2][4][2];
        #pragma unroll
        for (int rtI = 0; rtI < 2; ++rtI)
            #pragma unroll
            for (int g = 0; g < 4; ++g)
                #pragma unroll
                for (int ct = 0; ct < 2; ++ct)
                    acc[rtI][g][ct] = (f32x4){0.f, 0.f, 0.f, 0.f};

        for (int kk = 0; kk < 8; ++kk) {
            const int cs = kk * 4 + lk;
            const int o0 = lcol * 256        + ((cs ^ lcol) << 3);
            const int o1 = (16 + lcol) * 256 + ((cs ^ lcol) << 3);

            // ---- ih phase ----
            bf16x8 ax0h, ax0l, ax1h, ax1l;
            if (lv0) { ax0h = *(const bf16x8*)&xH[o0]; ax0l = *(const bf16x8*)&xL[o0]; }
            if (lv1) { ax1h = *(const bf16x8*)&xH[o1]; ax1l = *(const bf16x8*)&xL[o1]; }
            #pragma unroll
            for (int g = 0; g < 3; ++g) {
                #pragma unroll
                for (int ct = 0; ct < 2; ++ct) {
                    bf16x8 B = *(const bf16x8*)&BFw[((ct * 48 + g * 8 + kk) << 9) + (lane << 3)];
                    if (lv0) {
                        acc[0][g][ct] = __builtin_amdgcn_mfma_f32_16x16x32_bf16(ax0h, B, acc[0][g][ct], 0, 0, 0);
                        acc[0][g][ct] = __builtin_amdgcn_mfma_f32_16x16x32_bf16(ax0l, B, acc[0][g][ct], 0, 0, 0);
                    }
                    if (lv1) {
                        acc[1][g][ct] = __builtin_amdgcn_mfma_f32_16x16x32_bf16(ax1h, B, acc[1][g][ct], 0, 0, 0);
                        acc[1][g][ct] = __builtin_amdgcn_mfma_f32_16x16x32_bf16(ax1l, B, acc[1][g][ct], 0, 0, 0);
                    }
                }
            }
            // ---- hh phase ----
            bf16x8 ah0h, ah0l, ah1h, ah1l;
            if (lv0) { ah0h = *(const bf16x8*)&hH[o0]; ah0l = *(const bf16x8*)&hL[o0]; }
            if (lv1) { ah1h = *(const bf16x8*)&hH[o1]; ah1l = *(const bf16x8*)&hL[o1]; }
            #pragma unroll
            for (int g = 0; g < 3; ++g) {
                const int ai = (g == 2) ? 3 : g;
                #pragma unroll
                for (int ct = 0; ct < 2; ++ct) {
                    bf16x8 B = *(const bf16x8*)&BFw[((ct * 48 + (g + 3) * 8 + kk) << 9) + (lane << 3)];
                    if (lv0) {
                        acc[0][ai][ct] = __builtin_amdgcn_mfma_f32_16x16x32_bf16(ah0h, B, acc[0][ai][ct], 0, 0, 0);
                        acc[0][ai][ct] = __builtin_amdgcn_mfma_f32_16x16x32_bf16(ah0l, B, acc[0][ai][ct], 0, 0, 0);
                    }
                    if (lv1) {
                        acc[1][ai][ct] = __builtin_amdgcn_mfma_f32_16x16x32_bf16(ah1h, B, acc[1][ai][ct], 0, 0, 0);
                        acc[1][ai][ct] = __builtin_amdgcn_mfma_f32_16x16x32_bf16(ah1l, B, acc[1][ai][ct], 0, 0, 0);
                    }
                }
            }
        }
        __syncthreads();                             // all h reads done before rewrite

        // ---- gates + emit + h update ----
        #pragma unroll
        for (int rtI = 0; rtI < 2; ++rtI) {
            if (!(rtI ? lv1 : lv0)) continue;
            #pragma unroll
            for (int q = 0; q < 4; ++q) {
                int row = rtI * 16 + lk * 4 + q;
                if (!alive[row]) continue;
                int em = (rt[row] == re[row]);
                #pragma unroll
                for (int ct = 0; ct < 2; ++ct) {
                    int c = w * 32 + ct * 16 + lcol;
                    float gr  = acc[rtI][0][ct][q] + bR[ct];
                    float gz  = acc[rtI][1][ct][q] + bZ[ct];
                    float gin = acc[rtI][2][ct][q] + bIN[ct];
                    float ghn = acc[rtI][3][ct][q] + bHN[ct];
                    float rr = sigmoidf_(gr);
                    float zz = sigmoidf_(gz);
                    float nn = tanhf_(gin + rr * ghn);
                    int o = row * 256 + (((c >> 3) ^ (row & 15)) << 3) + (c & 7);
                    float hold = bf2f(hH[o]) + bf2f(hL[o]);
                    float hnew = (1.f - zz) * nn + zz * hold;
                    if (em) {
                        out[((size_t)rb[row] * TT + rp[row]) * HH + c] = hnew;
                        hnew = 0.f;                  // reset slot for next segment
                    }
                    uint16_t hi = f2bf(hnew);
                    hH[o] = hi;
                    hL[o] = f2bf(hnew - bf2f(hi));
                }
            }
        }
        __syncthreads();                             // h/meta stable before next pop
    }
}

extern "C" void kernel_launch(void* const* d_in, const int* in_sizes, int n_in,
                              void* d_out, int out_size, void* d_ws, size_t ws_size,
                              hipStream_t stream) {
    const float* x   = (const float*)d_in[0];
    const int*   seg = (const int*)d_in[1];
    const int*   len = (const int*)d_in[2];
    const float* Wih = (const float*)d_in[3];
    const float* Whh = (const float*)d_in[4];
    const float* bih = (const float*)d_in[5];
    const float* bhh = (const float*)d_in[6];
    float* out = (float*)d_out;

    int*      counters = (int*)d_ws;
    int4*     recs     = (int4*)((char*)d_ws + REC_OFF);
    int4*     recs2    = (int4*)((char*)d_ws + REC2_OFF);
    uint16_t* BF       = (uint16_t*)((char*)d_ws + BF_OFF);

    static int lds_set = 0;
    if (!lds_set) {
        hipFuncSetAttribute(reinterpret_cast<const void*>(&k_main),
                            hipFuncAttributeMaxDynamicSharedMemorySize, 65536);
        lds_set = 1;
    }

    hipMemsetAsync(d_out, 0, (size_t)out_size * sizeof(float), stream);
    hipMemsetAsync(d_ws, 0, 64, stream);

    k_prep<<<192, 256, 0, stream>>>(Wih, Whh, BF);
    k_meta<<<BB, 256, 0, stream>>>(seg, len, recs, counters, out + (size_t)BB * TT * HH);
    k_sort<<<1, 1024, 0, stream>>>(recs, recs2, counters);
    k_main<<<512, 512, 65536, stream>>>(x, BF, bih, bhh, recs2, counters, out);
}

// Round 7
// 642.283 us; speedup vs baseline: 1.4145x; 1.4145x over previous
//
#include <hip/hip_runtime.h>
#include <cstdint>
#include <cstddef>

#define TT 2048
#define BB 32
#define DD 256
#define HH 256

using bf16x8 = __attribute__((ext_vector_type(8))) short;
using f32x4  = __attribute__((ext_vector_type(4))) float;

// ws layout:
// [0..63]    counters: [0]=nseg, [1]=queue head
// [REC_OFF]  int4 records (unsorted), cap 32768
// [REC2_OFF] int4 records (sorted desc by length)
// [BF_OFF]   fragmentized bf16 weights: 768 frags x 512 ushort (768 KB)
static const size_t REC_OFF  = 64;
static const size_t REC2_OFF = REC_OFF  + (size_t)32768 * 16;
static const size_t BF_OFF   = REC2_OFF + (size_t)32768 * 16;

__device__ __forceinline__ uint16_t f2bf(float v) {
    unsigned int u = __float_as_uint(v);
    u += 0x7FFF + ((u >> 16) & 1);          // RNE
    return (uint16_t)(u >> 16);
}
__device__ __forceinline__ float bf2f(uint16_t h) {
    return __uint_as_float(((unsigned int)h) << 16);
}
__device__ __forceinline__ float sigmoidf_(float v) {
    return 1.f / (1.f + __expf(-v));
}
__device__ __forceinline__ float tanhf_(float v) {
    v = fminf(fmaxf(v, -30.f), 30.f);
    float e = __expf(-2.f * v);
    return (1.f - e) / (1.f + e);
}

// ---------------- weights f32 -> bf16 MFMA fragments ----------------
// frag f = (w*2+ct)*48 + g*8 + kk ; lane holds B[col=w*32+ct*16+(lane&15)][k0..k0+8)
// k0 = kk*32 + (lane>>4)*8 ; g in 0..5 = {ih_r, ih_z, ih_n, hh_r, hh_z, hh_n}
__global__ void k_prep(const float* __restrict__ Wih, const float* __restrict__ Whh,
                       uint16_t* __restrict__ BF) {
    int i = blockIdx.x * 256 + threadIdx.x;      // 0..49151
    if (i >= 768 * 64) return;
    int lane = i & 63, f = i >> 6;
    int kk = f & 7, t = f >> 3;
    int g = t % 6, wct = t / 6;
    int w = wct >> 1, ct = wct & 1;
    int col = w * 32 + ct * 16 + (lane & 15);
    int k0 = kk * 32 + ((lane >> 4) << 3);
    const float* W = (g < 3) ? Wih : Whh;
    const float* src = W + (size_t)((g % 3) * 256 + col) * DD + k0;
    bf16x8 v;
    #pragma unroll
    for (int e = 0; e < 8; ++e) v[e] = (short)f2bf(src[e]);
    *(bf16x8*)&BF[(size_t)f * 512 + lane * 8] = v;
}

// ---------------- per-batch segment metadata ----------------
__global__ void k_meta(const int* __restrict__ seg, const int* __restrict__ lengths,
                       int4* __restrict__ recs, int* __restrict__ counters,
                       float* __restrict__ outIdx) {
    int b = blockIdx.x;
    int tid = threadIdx.x;                          // 256 threads
    int len = lengths[b];
    const int* s = seg + (size_t)b * TT;
    const int CH = TT / 256;                        // 8
    int t0 = tid * CH;

    int cnt = 0;
    for (int t = t0; t < t0 + CH; ++t)
        cnt += (s[t] == 0 && t < len) ? 1 : 0;

    __shared__ int part[256];
    __shared__ int base;
    part[tid] = cnt;
    __syncthreads();
    if (tid == 0) {
        int run = 0;
        for (int i = 0; i < 256; ++i) { int v = part[i]; part[i] = run; run += v; }
        base = atomicAdd(&counters[0], run);
        outIdx[b] = (float)run;                     // idx[b] output (as float)
    }
    __syncthreads();

    int run = part[tid];
    for (int t = t0; t < t0 + CH; ++t) {
        if (s[t] == 0 && t < len) {
            int ss = t - 1;
            while (ss >= 0 && s[ss] != 0) --ss;     // previous boundary (any, incl. dead)
            int slot = base + run;
            if (slot < 32768) recs[slot] = make_int4(b, ss + 1, t, run);
            ++run;
        }
    }
}

// ---------------- counting sort by segment length, descending ----------------
__global__ void k_sort(const int4* __restrict__ recs, int4* __restrict__ recs2,
                       const int* __restrict__ counters) {
    __shared__ int hist[64];
    __shared__ int off[64];
    int n = counters[0]; if (n > 32768) n = 32768;
    int tid = threadIdx.x;   // 1024
    if (tid < 64) hist[tid] = 0;
    __syncthreads();
    for (int i = tid; i < n; i += 1024) {
        int4 r = recs[i];
        int len = r.z - r.y + 1;
        atomicAdd(&hist[min(len, 63)], 1);
    }
    __syncthreads();
    if (tid == 0) {
        int run = 0;
        for (int b = 63; b >= 0; --b) { off[b] = run; run += hist[b]; }
    }
    __syncthreads();
    if (tid < 64) hist[tid] = 0;     // reuse as cursors
    __syncthreads();
    for (int i = tid; i < n; i += 1024) {
        int4 r = recs[i];
        int len = r.z - r.y + 1;
        int b = min(len, 63);
        int pos = off[b] + atomicAdd(&hist[b], 1);
        recs2[pos] = r;
    }
}

// ---------------- persistent MFMA segment-packed GRU, M=32 ----------------
// 512 thr = 8 waves; wave w owns H-cols [w*32,(w+1)*32); 2 row-tiles of 16.
// __launch_bounds__(512,2): 256-reg unified budget. acc (64 AGPR) + ~90 VGPR
// transients fit with large headroom -> ZERO scratch spill (R3/R5 lesson:
// capping at 128 converts pressure into ~500 MB of scratch traffic).
// 8-wave WG means 1 WG/CU either way; we buy registers, not occupancy.
__global__ __launch_bounds__(512, 2) void k_main(
    const float* __restrict__ x, const uint16_t* __restrict__ BF,
    const float* __restrict__ b_ih, const float* __restrict__ b_hh,
    const int4* __restrict__ recs, int* __restrict__ counters,
    float* __restrict__ out)
{
    extern __shared__ uint16_t smem[];               // 64 KiB dynamic
    uint16_t* xH = smem;                             // [32][256]
    uint16_t* xL = smem + 8192;
    uint16_t* hH = smem + 16384;
    uint16_t* hL = smem + 24576;
    __shared__ int rb[32], rt[32], re[32], rp[32], alive[32];
    __shared__ int liveRTS[2];
    __shared__ int anyAliveS, nsegS;

    const int tid  = threadIdx.x;
    const int lane = tid & 63;
    const int w    = tid >> 6;
    const int lcol = lane & 15;
    const int lk   = lane >> 4;

    for (int i = tid; i < 8192; i += 512) { hH[i] = 0; hL[i] = 0; }
    if (tid < 32) alive[tid] = 0;
    if (tid == 0) nsegS = min(counters[0], 32768);
    __syncthreads();
    const int nseg = nsegS;

    float bR[2], bZ[2], bIN[2], bHN[2];
    #pragma unroll
    for (int ct = 0; ct < 2; ++ct) {
        int c = w * 32 + ct * 16 + lcol;
        bR[ct]  = b_ih[c]       + b_hh[c];
        bZ[ct]  = b_ih[256 + c] + b_hh[256 + c];
        bIN[ct] = b_ih[512 + c];
        bHN[ct] = b_hh[512 + c];
    }
    const uint16_t* BFw = BF + (size_t)w * 96 * 512;

    for (;;) {
        // ---- pop/advance: wave 0, lane m owns slot m ----
        if (tid < 32) {
            int m = tid;
            int al = alive[m];
            if (al) { if (rt[m] >= re[m]) al = 0; else rt[m] = rt[m] + 1; }
            unsigned long long deadm = __ballot(!al);
            int base = 0;
            if (tid == 0 && deadm) base = atomicAdd(&counters[1], __popcll(deadm));
            base = __shfl(base, 0);
            if (!al) {
                int rank = __popcll(deadm & ((1ULL << tid) - 1));
                int sidx = base + rank;
                if (sidx < nseg) {
                    int4 r = recs[sidx];
                    rb[m] = r.x; rt[m] = r.y; re[m] = r.z; rp[m] = r.w;
                    al = 1;                          // h row is zero already
                }
            }
            alive[m] = al;
            unsigned long long am = __ballot(al);
            if (tid == 0) anyAliveS = (am != 0ULL) ? 1 : 0;
            if (tid < 2) liveRTS[tid] = (int)((am >> (tid * 16)) & 0xFFFFULL);
        }
        __syncthreads();
        if (!anyAliveS) break;

        // ---- stage x rows: 16 threads/row, hi/lo split, swizzled ----
        {
            int row = tid >> 4, j = tid & 15;
            if (alive[row]) {
                const float* xp = x + ((size_t)rb[row] * TT + rt[row]) * DD + j * 16;
                #pragma unroll
                for (int u = 0; u < 2; ++u) {
                    float4 a = *(const float4*)(xp + u * 8);
                    float4 b = *(const float4*)(xp + u * 8 + 4);
                    float vv[8] = {a.x, a.y, a.z, a.w, b.x, b.y, b.z, b.w};
                    bf16x8 vh, vl;
                    #pragma unroll
                    for (int e = 0; e < 8; ++e) {
                        uint16_t hi = f2bf(vv[e]);
                        vh[e] = (short)hi;
                        vl[e] = (short)f2bf(vv[e] - bf2f(hi));
                    }
                    int cs = j * 2 + u;
                    int o = row * 256 + ((cs ^ (row & 15)) << 3);
                    *(bf16x8*)&xH[o] = vh;
                    *(bf16x8*)&xL[o] = vl;
                }
            }
        }
        __syncthreads();

        const int lv0 = liveRTS[0], lv1 = liveRTS[1];

        f32x4 acc[2][4][2];
        #pragma unroll
        for (int rtI = 0; rtI < 2; ++rtI)
            #pragma unroll
            for (int g = 0; g < 4; ++g)
                #pragma unroll
                for (int ct = 0; ct < 2; ++ct)
                    acc[rtI][g][ct] = (f32x4){0.f, 0.f, 0.f, 0.f};

        for (int kk = 0; kk < 8; ++kk) {
            const int cs = kk * 4 + lk;
            const int o0 = lcol * 256        + ((cs ^ lcol) << 3);
            const int o1 = (16 + lcol) * 256 + ((cs ^ lcol) << 3);

            // ---- ih phase ----
            bf16x8 ax0h, ax0l, ax1h, ax1l;
            if (lv0) { ax0h = *(const bf16x8*)&xH[o0]; ax0l = *(const bf16x8*)&xL[o0]; }
            if (lv1) { ax1h = *(const bf16x8*)&xH[o1]; ax1l = *(const bf16x8*)&xL[o1]; }
            #pragma unroll
            for (int g = 0; g < 3; ++g) {
                #pragma unroll
                for (int ct = 0; ct < 2; ++ct) {
                    bf16x8 B = *(const bf16x8*)&BFw[((ct * 48 + g * 8 + kk) << 9) + (lane << 3)];
                    if (lv0) {
                        acc[0][g][ct] = __builtin_amdgcn_mfma_f32_16x16x32_bf16(ax0h, B, acc[0][g][ct], 0, 0, 0);
                        acc[0][g][ct] = __builtin_amdgcn_mfma_f32_16x16x32_bf16(ax0l, B, acc[0][g][ct], 0, 0, 0);
                    }
                    if (lv1) {
                        acc[1][g][ct] = __builtin_amdgcn_mfma_f32_16x16x32_bf16(ax1h, B, acc[1][g][ct], 0, 0, 0);
                        acc[1][g][ct] = __builtin_amdgcn_mfma_f32_16x16x32_bf16(ax1l, B, acc[1][g][ct], 0, 0, 0);
                    }
                }
            }
            // ---- hh phase ----
            bf16x8 ah0h, ah0l, ah1h, ah1l;
            if (lv0) { ah0h = *(const bf16x8*)&hH[o0]; ah0l = *(const bf16x8*)&hL[o0]; }
            if (lv1) { ah1h = *(const bf16x8*)&hH[o1]; ah1l = *(const bf16x8*)&hL[o1]; }
            #pragma unroll
            for (int g = 0; g < 3; ++g) {
                const int ai = (g == 2) ? 3 : g;
                #pragma unroll
                for (int ct = 0; ct < 2; ++ct) {
                    bf16x8 B = *(const bf16x8*)&BFw[((ct * 48 + (g + 3) * 8 + kk) << 9) + (lane << 3)];
                    if (lv0) {
                        acc[0][ai][ct] = __builtin_amdgcn_mfma_f32_16x16x32_bf16(ah0h, B, acc[0][ai][ct], 0, 0, 0);
                        acc[0][ai][ct] = __builtin_amdgcn_mfma_f32_16x16x32_bf16(ah0l, B, acc[0][ai][ct], 0, 0, 0);
                    }
                    if (lv1) {
                        acc[1][ai][ct] = __builtin_amdgcn_mfma_f32_16x16x32_bf16(ah1h, B, acc[1][ai][ct], 0, 0, 0);
                        acc[1][ai][ct] = __builtin_amdgcn_mfma_f32_16x16x32_bf16(ah1l, B, acc[1][ai][ct], 0, 0, 0);
                    }
                }
            }
        }
        __syncthreads();                             // all h reads done before rewrite

        // ---- gates + emit + h update ----
        #pragma unroll
        for (int rtI = 0; rtI < 2; ++rtI) {
            if (!(rtI ? lv1 : lv0)) continue;
            #pragma unroll
            for (int q = 0; q < 4; ++q) {
                int row = rtI * 16 + lk * 4 + q;
                if (!alive[row]) continue;
                int em = (rt[row] == re[row]);
                #pragma unroll
                for (int ct = 0; ct < 2; ++ct) {
                    int c = w * 32 + ct * 16 + lcol;
                    float gr  = acc[rtI][0][ct][q] + bR[ct];
                    float gz  = acc[rtI][1][ct][q] + bZ[ct];
                    float gin = acc[rtI][2][ct][q] + bIN[ct];
                    float ghn = acc[rtI][3][ct][q] + bHN[ct];
                    float rr = sigmoidf_(gr);
                    float zz = sigmoidf_(gz);
                    float nn = tanhf_(gin + rr * ghn);
                    int o = row * 256 + (((c >> 3) ^ (row & 15)) << 3) + (c & 7);
                    float hold = bf2f(hH[o]) + bf2f(hL[o]);
                    float hnew = (1.f - zz) * nn + zz * hold;
                    if (em) {
                        out[((size_t)rb[row] * TT + rp[row]) * HH + c] = hnew;
                        hnew = 0.f;                  // reset slot for next segment
                    }
                    uint16_t hi = f2bf(hnew);
                    hH[o] = hi;
                    hL[o] = f2bf(hnew - bf2f(hi));
                }
            }
        }
        __syncthreads();                             // h/meta stable before next pop
    }
}

extern "C" void kernel_launch(void* const* d_in, const int* in_sizes, int n_in,
                              void* d_out, int out_size, void* d_ws, size_t ws_size,
                              hipStream_t stream) {
    const float* x   = (const float*)d_in[0];
    const int*   seg = (const int*)d_in[1];
    const int*   len = (const int*)d_in[2];
    const float* Wih = (const float*)d_in[3];
    const float* Whh = (const float*)d_in[4];
    const float* bih = (const float*)d_in[5];
    const float* bhh = (const float*)d_in[6];
    float* out = (float*)d_out;

    int*      counters = (int*)d_ws;
    int4*     recs     = (int4*)((char*)d_ws + REC_OFF);
    int4*     recs2    = (int4*)((char*)d_ws + REC2_OFF);
    uint16_t* BF       = (uint16_t*)((char*)d_ws + BF_OFF);

    static int lds_set = 0;
    if (!lds_set) {
        hipFuncSetAttribute(reinterpret_cast<const void*>(&k_main),
                            hipFuncAttributeMaxDynamicSharedMemorySize, 65536);
        lds_set = 1;
    }

    hipMemsetAsync(d_out, 0, (size_t)out_size * sizeof(float), stream);
    hipMemsetAsync(d_ws, 0, 64, stream);

    k_prep<<<192, 256, 0, stream>>>(Wih, Whh, BF);
    k_meta<<<BB, 256, 0, stream>>>(seg, len, recs, counters, out + (size_t)BB * TT * HH);
    k_sort<<<1, 1024, 0, stream>>>(recs, recs2, counters);
    k_main<<<256, 512, 65536, stream>>>(x, BF, bih, bhh, recs2, counters, out);
}